// Round 4
// baseline (174.484 us; speedup 1.0000x reference)
//
#include <hip/hip_runtime.h>
#include <hip/hip_bf16.h>

#define BATCH   2
#define L_SEQ   2048
#define DMODEL  1024
#define NHEADS  16
#define DHEAD   64
#define SEG     (BATCH*NHEADS*L_SEQ*DHEAD)   // 4,194,304 elements per q/k/v segment

typedef __attribute__((ext_vector_type(8)))  short bf16x8;
typedef __attribute__((ext_vector_type(4)))  float f32x4;
typedef __attribute__((ext_vector_type(16))) float f32x16;
typedef __attribute__((ext_vector_type(4)))  unsigned int u32x4;

__device__ __forceinline__ unsigned short f2b(float f) {
    unsigned int u = __float_as_uint(f);
    return (unsigned short)((u + 0x7FFFu + ((u >> 16) & 1u)) >> 16);   // RNE
}
__device__ __forceinline__ unsigned int pk2(float a, float b) {
    __hip_bfloat162 h = __float22bfloat162_rn(make_float2(a, b));
    return *(unsigned int*)&h;
}
__device__ __forceinline__ void glds16(const unsigned short* g, unsigned short* l) {
    __builtin_amdgcn_global_load_lds(
        (const __attribute__((address_space(1))) unsigned int*)g,
        (__attribute__((address_space(3))) unsigned int*)l, 16, 0, 0);
}

// ---------------------------------------------------------------------------
// prep: 5120 blocks. 0..4095 cast x->bf16; 4096..4863 transpose-cast w_qkv;
// 4864..5119 transpose-cast w_proj.
// ---------------------------------------------------------------------------
__device__ __forceinline__ void tcast64(const float* __restrict__ in,
                                        unsigned short* __restrict__ out,
                                        int K, int N, int bx, int by, int t) {
    __shared__ unsigned short T[64][65];
    const int k0 = by * 64, n0 = bx * 64;
    const int r = t >> 4, c4 = (t & 15) * 4;
#pragma unroll
    for (int rep = 0; rep < 4; ++rep) {
        int kk = rep * 16 + r;
        float4 f = *(const float4*)&in[(size_t)(k0 + kk) * N + n0 + c4];
        T[kk][c4 + 0] = f2b(f.x);
        T[kk][c4 + 1] = f2b(f.y);
        T[kk][c4 + 2] = f2b(f.z);
        T[kk][c4 + 3] = f2b(f.w);
    }
    __syncthreads();
#pragma unroll
    for (int rep = 0; rep < 4; ++rep) {
        int nn = rep * 16 + r;
        ushort4 o;
        o.x = T[c4 + 0][nn];
        o.y = T[c4 + 1][nn];
        o.z = T[c4 + 2][nn];
        o.w = T[c4 + 3][nn];
        *(ushort4*)&out[(size_t)(n0 + nn) * K + k0 + c4] = o;
    }
}

__global__ __launch_bounds__(256)
void prep(const float* __restrict__ x, const float* __restrict__ wqkv,
          const float* __restrict__ wproj, unsigned short* __restrict__ xb,
          unsigned short* __restrict__ wqkvT, unsigned short* __restrict__ wprojT) {
    const int id = blockIdx.x, t = threadIdx.x;
    if (id < 4096) {
        int i = id * 1024 + t * 4;
        float4 f = *(const float4*)&x[i];
        ushort4 o;
        o.x = f2b(f.x); o.y = f2b(f.y); o.z = f2b(f.z); o.w = f2b(f.w);
        *(ushort4*)&xb[i] = o;
    } else if (id < 4864) {
        int lid = id - 4096;
        tcast64(wqkv, wqkvT, DMODEL, 3 * DMODEL, lid % 48, lid / 48, t);
    } else {
        int lid = id - 4864;
        tcast64(wproj, wprojT, DMODEL, DMODEL, lid & 15, lid >> 4, t);
    }
}

// ---------------------------------------------------------------------------
// QKV GEMM: C = xb[4096,1024] @ wqkvT[3072,1024]^T. 128x128 tile, BK=64.
// 2-phase dbuf pipeline (stage next FIRST, compute, ONE syncthreads/K-tile).
// glds16 staging + XOR source-chunk swizzle. XCD remap (grid 24x32=768).
// Epilogue: acc -> swizzled 32KB LDS tile -> coalesced 16B stores.
// n0<2048: Q/K [bh][l][d] (Q scaled 0.125*log2e). n0>=2048: operand-swapped
// MFMAs (acc = C^T) -> V^T [bh][d][L].
// ---------------------------------------------------------------------------
__global__ __launch_bounds__(256)
void gemm_qkv(const unsigned short* __restrict__ A, const unsigned short* __restrict__ Bt,
              unsigned short* __restrict__ Cb) {
    __shared__ unsigned short SLDS[2 * 128 * 128];   // 64 KB: 2 bufs x (A 16K + B 16K)

    const int t = threadIdx.x;
    const int lane = t & 63, wave = t >> 6;
    const int quad = lane >> 4, l16 = lane & 15;
    const int wm = (wave >> 1) * 64, wn = (wave & 1) * 64;
    // XCD remap: grid must be 24x32 (768 blocks)
    const int id = blockIdx.y * gridDim.x + blockIdx.x;
    const int xcd = id & 7, sq = id >> 3;          // sq in [0,96)
    const int m0 = (xcd * 4 + sq / 24) * 128;      // 4 m-rows per XCD
    const int n0 = (sq % 24) * 128;                // x-major within XCD
    const bool vrole = (n0 >= 2048);

    const int gsw = (lane & 7) ^ (lane >> 3);
    const unsigned short* ga[4];
    const unsigned short* gb[4];
    int ldA[4], ldB[4];
#pragma unroll
    for (int i = 0; i < 4; ++i) {
        int row = wave * 32 + i * 8 + (lane >> 3);
        ga[i] = &A[(size_t)(m0 + row) * DMODEL + gsw * 8];
        gb[i] = &Bt[(size_t)(n0 + row) * DMODEL + gsw * 8];
        ldA[i] = (wave * 32 + i * 8) * 64;
        ldB[i] = 8192 + (wave * 32 + i * 8) * 64;
    }
    const int sx = l16 & 7;

    f32x4 acc[4][4];
#pragma unroll
    for (int i = 0; i < 4; ++i)
#pragma unroll
        for (int j = 0; j < 4; ++j)
#pragma unroll
            for (int r = 0; r < 4; ++r) acc[i][j][r] = 0.0f;

    // prologue: K-tile 0 -> buf 0
#pragma unroll
    for (int i = 0; i < 4; ++i) {
        glds16(ga[i], &SLDS[ldA[i]]);
        glds16(gb[i], &SLDS[ldB[i]]);
    }
    __syncthreads();

    int cur = 0;
    for (int kt = 0; kt < 16; ++kt) {
        // issue next tile's stage FIRST (into the other buffer)
        if (kt < 15) {
            const int ko = (kt + 1) * 64;
            unsigned short* dst = &SLDS[(cur ^ 1) * 16384];
#pragma unroll
            for (int i = 0; i < 4; ++i) {
                glds16(ga[i] + ko, dst + ldA[i]);
                glds16(gb[i] + ko, dst + ldB[i]);
            }
        }
        // compute current tile from buf[cur]
        const unsigned short* Asm = &SLDS[cur * 16384];
        const unsigned short* Bsm = Asm + 8192;
#pragma unroll
        for (int s = 0; s < 2; ++s) {
            bf16x8 af[4], bfr[4];
#pragma unroll
            for (int i = 0; i < 4; ++i)
                af[i] = *(const bf16x8*)&Asm[(wm + i * 16 + l16) * 64 + ((4 * s + quad) ^ sx) * 8];
#pragma unroll
            for (int j = 0; j < 4; ++j)
                bfr[j] = *(const bf16x8*)&Bsm[(wn + j * 16 + l16) * 64 + ((4 * s + quad) ^ sx) * 8];
            __builtin_amdgcn_s_setprio(1);
            if (!vrole) {
#pragma unroll
                for (int i = 0; i < 4; ++i)
#pragma unroll
                    for (int j = 0; j < 4; ++j)
                        acc[i][j] = __builtin_amdgcn_mfma_f32_16x16x32_bf16(af[i], bfr[j], acc[i][j], 0, 0, 0);
            } else {   // C^T: rows=features, cols=tokens
#pragma unroll
                for (int i = 0; i < 4; ++i)
#pragma unroll
                    for (int j = 0; j < 4; ++j)
                        acc[i][j] = __builtin_amdgcn_mfma_f32_16x16x32_bf16(bfr[j], af[i], acc[i][j], 0, 0, 0);
            }
            __builtin_amdgcn_s_setprio(0);
        }
        __syncthreads();   // vmcnt(0)+lgkmcnt(0)+barrier: next buf ready, reads done
        cur ^= 1;
    }

    // ---- epilogue: acc -> swizzled LDS tile [128][128] -> coalesced stores
    const float qscale = 0.1803368801111244f;   // 0.125 * log2(e)
    const float scl = (!vrole && n0 < 1024) ? qscale : 1.0f;
#pragma unroll
    for (int i = 0; i < 4; ++i)
#pragma unroll
        for (int r = 0; r < 4; ++r) {
#pragma unroll
            for (int j = 0; j < 4; ++j) {
                int row_l, col_l;
                if (!vrole) {            // [token][feature]
                    row_l = wm + i * 16 + quad * 4 + r;
                    col_l = wn + j * 16 + l16;
                } else {                 // [feature][token] (acc is C^T)
                    row_l = wn + j * 16 + quad * 4 + r;
                    col_l = wm + i * 16 + l16;
                }
                int key = row_l & 7;
                SLDS[row_l * 128 + (((col_l >> 3) ^ key) * 8) + (col_l & 7)] =
                    f2b(acc[i][j][r] * scl);
            }
        }
    __syncthreads();

    const int s0 = n0 >> 10;        // 0=Q, 1=K (vrole handled separately)
    const int bb = m0 >> 11;        // batch index (tile never crosses)
#pragma unroll
    for (int it = 0; it < 4; ++it) {
        int row = it * 32 + (t >> 3);
        int c = t & 7;
        int key = row & 7;
        bf16x8 v0 = *(const bf16x8*)&SLDS[row * 128 + ((c ^ key) * 8)];
        bf16x8 v1 = *(const bf16x8*)&SLDS[row * 128 + (((c + 8) ^ key) * 8)];
        if (!vrole) {
            int token = m0 + row, lp = token & (L_SEQ - 1);
            int n_a = n0 + c * 8,        h_a = (n_a >> 6) & 15, d_a = n_a & 63;
            int n_b = n0 + (c + 8) * 8,  h_b = (n_b >> 6) & 15, d_b = n_b & 63;
            size_t base = (size_t)s0 * SEG;
            *(bf16x8*)&Cb[base + (((size_t)(bb * NHEADS + h_a) * L_SEQ + lp) * DHEAD) + d_a] = v0;
            *(bf16x8*)&Cb[base + (((size_t)(bb * NHEADS + h_b) * L_SEQ + lp) * DHEAD) + d_b] = v1;
        } else {
            int fr = (n0 - 2048) + row;
            int h = fr >> 6, dd = fr & 63;
            int lp0 = (m0 & (L_SEQ - 1));
            size_t base = 2 * (size_t)SEG +
                          (((size_t)(bb * NHEADS + h) * DHEAD + dd) * L_SEQ) + lp0;
            *(bf16x8*)&Cb[base + c * 8]       = v0;
            *(bf16x8*)&Cb[base + (c + 8) * 8] = v1;
        }
    }
}

// ---------------------------------------------------------------------------
// proj GEMM: out = ao[4096,1024] @ wprojT[1024,1024]^T, fp32 store.
// 128x128 tile + 2-phase dbuf pipeline. Grid 8x32 = 256 blocks; XCD remap.
// ---------------------------------------------------------------------------
__global__ __launch_bounds__(256)
void gemm_proj(const unsigned short* __restrict__ A, const unsigned short* __restrict__ Bt,
               float* __restrict__ Cf) {
    __shared__ unsigned short SLDS[2 * 128 * 128];   // 64 KB

    const int t = threadIdx.x;
    const int lane = t & 63, wave = t >> 6;
    const int quad = lane >> 4, l16 = lane & 15;
    const int wm = (wave >> 1) * 64, wn = (wave & 1) * 64;
    // XCD remap: grid must be 8x32 (256 blocks)
    const int id = blockIdx.y * gridDim.x + blockIdx.x;
    const int xcd = id & 7, sq = id >> 3;          // sq in [0,32)
    const int m0 = (xcd * 4 + (sq >> 3)) * 128;    // 4 m-rows per XCD
    const int n0 = (sq & 7) * 128;

    const int gsw = (lane & 7) ^ (lane >> 3);
    const unsigned short* ga[4];
    const unsigned short* gb[4];
    int ldA[4], ldB[4];
#pragma unroll
    for (int i = 0; i < 4; ++i) {
        int row = wave * 32 + i * 8 + (lane >> 3);
        ga[i] = &A[(size_t)(m0 + row) * DMODEL + gsw * 8];
        gb[i] = &Bt[(size_t)(n0 + row) * DMODEL + gsw * 8];
        ldA[i] = (wave * 32 + i * 8) * 64;
        ldB[i] = 8192 + (wave * 32 + i * 8) * 64;
    }
    const int sx = l16 & 7;

    f32x4 acc[4][4];
#pragma unroll
    for (int i = 0; i < 4; ++i)
#pragma unroll
        for (int j = 0; j < 4; ++j)
#pragma unroll
            for (int r = 0; r < 4; ++r) acc[i][j][r] = 0.0f;

#pragma unroll
    for (int i = 0; i < 4; ++i) {
        glds16(ga[i], &SLDS[ldA[i]]);
        glds16(gb[i], &SLDS[ldB[i]]);
    }
    __syncthreads();

    int cur = 0;
    for (int kt = 0; kt < 16; ++kt) {
        if (kt < 15) {
            const int ko = (kt + 1) * 64;
            unsigned short* dst = &SLDS[(cur ^ 1) * 16384];
#pragma unroll
            for (int i = 0; i < 4; ++i) {
                glds16(ga[i] + ko, dst + ldA[i]);
                glds16(gb[i] + ko, dst + ldB[i]);
            }
        }
        const unsigned short* Asm = &SLDS[cur * 16384];
        const unsigned short* Bsm = Asm + 8192;
#pragma unroll
        for (int s = 0; s < 2; ++s) {
            bf16x8 af[4], bfr[4];
#pragma unroll
            for (int i = 0; i < 4; ++i)
                af[i] = *(const bf16x8*)&Asm[(wm + i * 16 + l16) * 64 + ((4 * s + quad) ^ sx) * 8];
#pragma unroll
            for (int j = 0; j < 4; ++j)
                bfr[j] = *(const bf16x8*)&Bsm[(wn + j * 16 + l16) * 64 + ((4 * s + quad) ^ sx) * 8];
            __builtin_amdgcn_s_setprio(1);
#pragma unroll
            for (int i = 0; i < 4; ++i)
#pragma unroll
                for (int j = 0; j < 4; ++j)
                    acc[i][j] = __builtin_amdgcn_mfma_f32_16x16x32_bf16(af[i], bfr[j], acc[i][j], 0, 0, 0);
            __builtin_amdgcn_s_setprio(0);
        }
        __syncthreads();
        cur ^= 1;
    }

#pragma unroll
    for (int i = 0; i < 4; ++i)
#pragma unroll
        for (int r = 0; r < 4; ++r) {
            int row = m0 + wm + i * 16 + quad * 4 + r;
#pragma unroll
            for (int j = 0; j < 4; ++j)
                Cf[(size_t)row * DMODEL + n0 + wn + j * 16 + l16] = acc[i][j][r];
        }
}

// ---------------------------------------------------------------------------
// Flash causal attention, 8-wave split + IN-REGISTER P redistribution:
// 32x32x16 MFMA, S^T form, fixed-max softmax (Q pre-scaled to log2 units).
// 1024 blocks = 32 bh x 32 q-tiles(64q), LPT. 8 waves: qh=w&1, kp=w>>1
// (32-key window per wave).
// NEW vs r3: P never touches LDS. After QK^T, lane l31 holds P[q=l31] for
// keys {8g+4hi+0..3}; the PV A-frag needs keys {16ks+8hi+0..7} = own group
// (2ks+hi) + partner-half's (lane^32) same group. 8x pk2 -> 8x shfl_xor(32)
// -> 8 cndmask assemble both PV frags in-register. Removes Psm (16 KB), its
// 32 KB/strip LDS traffic and the serial lgkm round-trip between QK^T & PV.
// LDS = Ksm 16K + Vsm 16K = 32 KB (+1K Rex). Merge in 2 rounds within 32 KB:
// kp{2,3} dump -> kp{0,1} add; kp1 dump -> kp0 add, normalize, store.
// ---------------------------------------------------------------------------
__global__ __launch_bounds__(512)
void attn_mfma(const unsigned short* __restrict__ Qg, const unsigned short* __restrict__ Kg,
               const unsigned short* __restrict__ Vg, unsigned short* __restrict__ Ao) {
    __shared__ unsigned short SLDS[16384];   // K 16KB | V 16KB; merge reuse: 32KB f32
    __shared__ float Rex[192];               // 6 groups x 32 rs partials
    unsigned short* Ksm = SLDS;              // keys: 128 rows x 8 chunks
    unsigned short* Vsm = SLDS + 8192;       // d: 64 rows x 16 key-chunks

    const int t = threadIdx.x;
    const int lane = t & 63, wave = t >> 6;        // 8 waves
    const int l31 = lane & 31, hi = lane >> 5;
    const int bh = blockIdx.x & 31;
    const int Qt = 31 - (blockIdx.x >> 5);         // heavy tiles first
    const int q0 = Qt * 64;
    const int qh = wave & 1, kp = wave >> 1;       // kp in [0,4): 32-key window
    const int wq0 = q0 + qh * 32;
    const int nstrip = (Qt >> 1) + 1;              // 128-key strips
    const int b = bh >> 4, h = bh & 15;
    const size_t qkbase = (size_t)bh * L_SEQ * DHEAD;
    const size_t vbase  = (size_t)bh * DHEAD * L_SEQ;

    // Q B-frags: n=q=l31(+wq0), k = ks*16 + hi*8 + j
    bf16x8 bq[4];
#pragma unroll
    for (int ks = 0; ks < 4; ++ks)
        bq[ks] = *(const bf16x8*)&Qg[qkbase + (size_t)(wq0 + l31) * DHEAD + ks * 16 + hi * 8];

    // staging assignments (512 threads: 2 rows each)
    const int kc0 = t & 7,  kr0 = (t >> 3) * 2;    // K: rows kr0..+1, chunk kc0
    const int vc0 = t & 15, vd0 = (t >> 4) * 2;    // V: d vd0..+1, chunk vc0

    f32x16 O0, O1;
#pragma unroll
    for (int r = 0; r < 16; ++r) { O0[r] = 0.0f; O1[r] = 0.0f; }
    float rs = 0.0f;

    bf16x8 gk[2], gv[2];
#pragma unroll
    for (int i = 0; i < 2; ++i) {
        gk[i] = *(const bf16x8*)&Kg[qkbase + (size_t)(kr0 + i) * DHEAD + kc0 * 8];
        gv[i] = *(const bf16x8*)&Vg[vbase + (size_t)(vd0 + i) * L_SEQ + vc0 * 8];
    }

    for (int s = 0; s < nstrip; ++s) {
        __syncthreads();   // prior strip's LDS reads complete
#pragma unroll
        for (int i = 0; i < 2; ++i) {
            *(bf16x8*)&Ksm[(kc0 * 128 + ((kr0 + i) ^ kc0)) * 8] = gk[i];
            *(bf16x8*)&Vsm[(vc0 * 64 + ((vd0 + i) ^ vc0)) * 8] = gv[i];
        }
        if (s + 1 < nstrip) {
            const int kn = (s + 1) * 128;
#pragma unroll
            for (int i = 0; i < 2; ++i) {
                gk[i] = *(const bf16x8*)&Kg[qkbase + (size_t)(kn + kr0 + i) * DHEAD + kc0 * 8];
                gv[i] = *(const bf16x8*)&Vg[vbase + (size_t)(vd0 + i) * L_SEQ + kn + vc0 * 8];
            }
        }
        __syncthreads();

        const int keybase = s * 128 + kp * 32;     // wave's 32-key window
        if (keybase <= wq0 + 31) {                 // wave-uniform condition
            // S^T = K·Q^T (rows=keys, cols=q), 32 keys x 32 q
            f32x16 ST;
#pragma unroll
            for (int r = 0; r < 16; ++r) ST[r] = 0.0f;
            __builtin_amdgcn_s_setprio(1);
#pragma unroll
            for (int ks = 0; ks < 4; ++ks) {
                const int c = ks * 2 + hi;
                const int rk = kp * 32 + l31;
                bf16x8 a = *(const bf16x8*)&Ksm[(c * 128 + (rk ^ c)) * 8];
                ST = __builtin_amdgcn_mfma_f32_32x32x16_bf16(a, bq[ks], ST, 0, 0, 0);
            }
            __builtin_amdgcn_s_setprio(0);

            if (keybase + 31 > wq0) {   // diagonal: causal mask
                const int qg = wq0 + l31;
#pragma unroll
                for (int r = 0; r < 16; ++r) {
                    int keyg = keybase + (r & 3) + 8 * (r >> 2) + 4 * hi;
                    if (keyg > qg) ST[r] = -1e30f;
                }
            }

            // fixed-max softmax, all in registers
            float p[16];
#pragma unroll
            for (int r = 0; r < 16; ++r) p[r] = __builtin_amdgcn_exp2f(ST[r]);
#pragma unroll
            for (int g = 0; g < 4; ++g)
                rs += ((p[4*g] + p[4*g+1]) + (p[4*g+2] + p[4*g+3]));

            // pack groups: wv[2g+i] = bf16 pair; lane owns keys {8g+4hi+0..3}
            unsigned int wv0 = pk2(p[0],  p[1]),  wv1 = pk2(p[2],  p[3]);
            unsigned int wv2 = pk2(p[4],  p[5]),  wv3 = pk2(p[6],  p[7]);
            unsigned int wv4 = pk2(p[8],  p[9]),  wv5 = pk2(p[10], p[11]);
            unsigned int wv6 = pk2(p[12], p[13]), wv7 = pk2(p[14], p[15]);
            // partner half (lane^32) same-index groups
            unsigned int xv0 = (unsigned)__shfl_xor((int)wv0, 32, 64);
            unsigned int xv1 = (unsigned)__shfl_xor((int)wv1, 32, 64);
            unsigned int xv2 = (unsigned)__shfl_xor((int)wv2, 32, 64);
            unsigned int xv3 = (unsigned)__shfl_xor((int)wv3, 32, 64);
            unsigned int xv4 = (unsigned)__shfl_xor((int)wv4, 32, 64);
            unsigned int xv5 = (unsigned)__shfl_xor((int)wv5, 32, 64);
            unsigned int xv6 = (unsigned)__shfl_xor((int)wv6, 32, 64);
            unsigned int xv7 = (unsigned)__shfl_xor((int)wv7, 32, 64);
            // assemble PV A-frags: pa(ks) = keys {16ks+8hi+0..7} at q=l31
            u32x4 d0, d1;
            d0[0] = hi ? xv2 : wv0;  d0[1] = hi ? xv3 : wv1;
            d0[2] = hi ? wv2 : xv0;  d0[3] = hi ? wv3 : xv1;
            d1[0] = hi ? xv6 : wv4;  d1[1] = hi ? xv7 : wv5;
            d1[2] = hi ? wv6 : xv4;  d1[3] = hi ? wv7 : xv5;
            bf16x8 pa0 = __builtin_bit_cast(bf16x8, d0);
            bf16x8 pa1 = __builtin_bit_cast(bf16x8, d1);

            // O += P·V  (wave's 32 keys)
            __builtin_amdgcn_s_setprio(1);
            {
                const int cv0 = kp * 4 + hi;        // ks=0
                bf16x8 v0 = *(const bf16x8*)&Vsm[(cv0 * 64 + (l31 ^ cv0)) * 8];
                bf16x8 v1 = *(const bf16x8*)&Vsm[(cv0 * 64 + ((32 + l31) ^ cv0)) * 8];
                O0 = __builtin_amdgcn_mfma_f32_32x32x16_bf16(pa0, v0, O0, 0, 0, 0);
                O1 = __builtin_amdgcn_mfma_f32_32x32x16_bf16(pa0, v1, O1, 0, 0, 0);
                const int cv1 = kp * 4 + 2 + hi;    // ks=1
                bf16x8 v2 = *(const bf16x8*)&Vsm[(cv1 * 64 + (l31 ^ cv1)) * 8];
                bf16x8 v3 = *(const bf16x8*)&Vsm[(cv1 * 64 + ((32 + l31) ^ cv1)) * 8];
                O0 = __builtin_amdgcn_mfma_f32_32x32x16_bf16(pa1, v2, O0, 0, 0, 0);
                O1 = __builtin_amdgcn_mfma_f32_32x32x16_bf16(pa1, v3, O1, 0, 0, 0);
            }
            __builtin_amdgcn_s_setprio(0);
        }
    }

    rs += __shfl_xor(rs, 32, 64);   // combine hi halves: full own-window sum, q=l31

    // ---- 2-round merge within 32 KB (linear softmax => pure adds) ----
    __syncthreads();                 // all PV reads of Vsm done
    float* Oex = (float*)SLDS;       // 4 groups x 32q x 64d f32 = 32768 B exactly
    // round 1: kp=2,3 dump; all kp!=0 record rs
    if (kp >= 2) {
        const int g = (qh * 2 + (kp - 2)) * 2048;
#pragma unroll
        for (int r = 0; r < 16; ++r) {
            int qloc = (r & 3) + 8 * (r >> 2) + 4 * hi;
            Oex[g + qloc * 64 + l31]      = O0[r];
            Oex[g + qloc * 64 + 32 + l31] = O1[r];
        }
    }
    if (kp != 0 && hi == 0) Rex[(qh * 3 + (kp - 1)) * 32 + l31] = rs;
    __syncthreads();
    if (kp < 2) {                    // kp0 += kp2, kp1 += kp3
        const int g = (qh * 2 + kp) * 2048;
#pragma unroll
        for (int r = 0; r < 16; ++r) {
            int qloc = (r & 3) + 8 * (r >> 2) + 4 * hi;
            O0[r] += Oex[g + qloc * 64 + l31];
            O1[r] += Oex[g + qloc * 64 + 32 + l31];
        }
    }
    __syncthreads();
    // round 2: kp=1 dumps accumulated partial
    if (kp == 1) {
        const int g = qh * 2048;
#pragma unroll
        for (int r = 0; r < 16; ++r) {
            int qloc = (r & 3) + 8 * (r >> 2) + 4 * hi;
            Oex[g + qloc * 64 + l31]      = O0[r];
            Oex[g + qloc * 64 + 32 + l31] = O1[r];
        }
    }
    __syncthreads();
    if (kp == 0) {
        float rs_tot = rs;
#pragma unroll
        for (int p = 0; p < 3; ++p) rs_tot += Rex[(qh * 3 + p) * 32 + l31];
        float linv = 1.0f / rs_tot;
        float lf[16];
#pragma unroll
        for (int r = 0; r < 16; ++r) {
            int qloc = (r & 3) + 8 * (r >> 2) + 4 * hi;
            O0[r] += Oex[qh * 2048 + qloc * 64 + l31];
            O1[r] += Oex[qh * 2048 + qloc * 64 + 32 + l31];
            lf[r] = __shfl(linv, qloc, 32);
        }
#pragma unroll
        for (int r = 0; r < 16; ++r) {
            int qloc = (r & 3) + 8 * (r >> 2) + 4 * hi;
            int token = wq0 + qloc;
            size_t ob = ((size_t)(b * L_SEQ + token)) * DMODEL + h * DHEAD;
            Ao[ob + l31]      = f2b(O0[r] * lf[r]);
            Ao[ob + 32 + l31] = f2b(O1[r] * lf[r]);
        }
    }
}

// ---------------------------------------------------------------------------
extern "C" void kernel_launch(void* const* d_in, const int* in_sizes, int n_in,
                              void* d_out, int out_size, void* d_ws, size_t ws_size,
                              hipStream_t stream) {
    const float* x      = (const float*)d_in[0];   // [B, L, D]
    const float* w_qkv  = (const float*)d_in[1];   // [D, 3D]
    const float* w_proj = (const float*)d_in[2];   // [D, D]
    // d_in[3] num_prefix_tokens: unused — reference mask reduces to pure causal.
    float* out = (float*)d_out;                    // [B, L, D] fp32

    unsigned short* ws     = (unsigned short*)d_ws;
    unsigned short* xb     = ws;                         // 4,194,304
    unsigned short* wqkvT  = xb + 4194304;               // 3,145,728  [3072][1024]
    unsigned short* wprojT = wqkvT + 3145728;            // 1,048,576  [1024][1024]
    unsigned short* qkv    = wprojT + 1048576;           // Q,K [bh][l][d]; V^T [bh][d][l]
    unsigned short* ao     = qkv + 3 * (size_t)SEG;      // 4,194,304

    prep<<<5120, 256, 0, stream>>>(x, w_qkv, w_proj, xb, wqkvT, wprojT);

    gemm_qkv<<<dim3(24, 32), 256, 0, stream>>>(xb, wqkvT, qkv);

    attn_mfma<<<1024, 512, 0, stream>>>(qkv, qkv + SEG, qkv + 2 * (size_t)SEG, ao);

    gemm_proj<<<dim3(8, 32), 256, 0, stream>>>(ao, wprojT, out);
}

// Round 5
// 161.453 us; speedup vs baseline: 1.0807x; 1.0807x over previous
//
#include <hip/hip_runtime.h>
#include <hip/hip_bf16.h>

#define BATCH   2
#define L_SEQ   2048
#define DMODEL  1024
#define NHEADS  16
#define DHEAD   64
#define SEG     (BATCH*NHEADS*L_SEQ*DHEAD)   // 4,194,304 elements per q/k/v segment

typedef __attribute__((ext_vector_type(8)))  short bf16x8;
typedef __attribute__((ext_vector_type(4)))  float f32x4;
typedef __attribute__((ext_vector_type(16))) float f32x16;

__device__ __forceinline__ unsigned short f2b(float f) {
    unsigned int u = __float_as_uint(f);
    return (unsigned short)((u + 0x7FFFu + ((u >> 16) & 1u)) >> 16);   // RNE
}
__device__ __forceinline__ unsigned int pk2(float a, float b) {
    __hip_bfloat162 h = __float22bfloat162_rn(make_float2(a, b));
    return *(unsigned int*)&h;
}
__device__ __forceinline__ void glds16(const unsigned short* g, unsigned short* l) {
    __builtin_amdgcn_global_load_lds(
        (const __attribute__((address_space(1))) unsigned int*)g,
        (__attribute__((address_space(3))) unsigned int*)l, 16, 0, 0);
}

// ---------------------------------------------------------------------------
// prep: 5120 blocks. 0..4095 cast x->bf16; 4096..4863 transpose-cast w_qkv;
// 4864..5119 transpose-cast w_proj.
// ---------------------------------------------------------------------------
__device__ __forceinline__ void tcast64(const float* __restrict__ in,
                                        unsigned short* __restrict__ out,
                                        int K, int N, int bx, int by, int t) {
    __shared__ unsigned short T[64][65];
    const int k0 = by * 64, n0 = bx * 64;
    const int r = t >> 4, c4 = (t & 15) * 4;
#pragma unroll
    for (int rep = 0; rep < 4; ++rep) {
        int kk = rep * 16 + r;
        float4 f = *(const float4*)&in[(size_t)(k0 + kk) * N + n0 + c4];
        T[kk][c4 + 0] = f2b(f.x);
        T[kk][c4 + 1] = f2b(f.y);
        T[kk][c4 + 2] = f2b(f.z);
        T[kk][c4 + 3] = f2b(f.w);
    }
    __syncthreads();
#pragma unroll
    for (int rep = 0; rep < 4; ++rep) {
        int nn = rep * 16 + r;
        ushort4 o;
        o.x = T[c4 + 0][nn];
        o.y = T[c4 + 1][nn];
        o.z = T[c4 + 2][nn];
        o.w = T[c4 + 3][nn];
        *(ushort4*)&out[(size_t)(n0 + nn) * K + k0 + c4] = o;
    }
}

__global__ __launch_bounds__(256)
void prep(const float* __restrict__ x, const float* __restrict__ wqkv,
          const float* __restrict__ wproj, unsigned short* __restrict__ xb,
          unsigned short* __restrict__ wqkvT, unsigned short* __restrict__ wprojT) {
    const int id = blockIdx.x, t = threadIdx.x;
    if (id < 4096) {
        int i = id * 1024 + t * 4;
        float4 f = *(const float4*)&x[i];
        ushort4 o;
        o.x = f2b(f.x); o.y = f2b(f.y); o.z = f2b(f.z); o.w = f2b(f.w);
        *(ushort4*)&xb[i] = o;
    } else if (id < 4864) {
        int lid = id - 4096;
        tcast64(wqkv, wqkvT, DMODEL, 3 * DMODEL, lid % 48, lid / 48, t);
    } else {
        int lid = id - 4864;
        tcast64(wproj, wprojT, DMODEL, DMODEL, lid & 15, lid >> 4, t);
    }
}

// ---------------------------------------------------------------------------
// QKV GEMM: C = xb[4096,1024] @ wqkvT[3072,1024]^T. 128x128 tile, BK=64.
// 2-phase dbuf pipeline (stage next FIRST, compute, ONE syncthreads/K-tile).
// glds16 staging + XOR source-chunk swizzle. XCD remap (grid 24x32=768).
// Epilogue: acc -> swizzled 32KB LDS tile -> coalesced 16B stores.
// n0<2048: Q/K [bh][l][d] (Q scaled 0.125*log2e). n0>=2048: operand-swapped
// MFMAs (acc = C^T) -> V^T [bh][d][L].
// ---------------------------------------------------------------------------
__global__ __launch_bounds__(256)
void gemm_qkv(const unsigned short* __restrict__ A, const unsigned short* __restrict__ Bt,
              unsigned short* __restrict__ Cb) {
    __shared__ unsigned short SLDS[2 * 128 * 128];   // 64 KB: 2 bufs x (A 16K + B 16K)

    const int t = threadIdx.x;
    const int lane = t & 63, wave = t >> 6;
    const int quad = lane >> 4, l16 = lane & 15;
    const int wm = (wave >> 1) * 64, wn = (wave & 1) * 64;
    // XCD remap: grid must be 24x32 (768 blocks)
    const int id = blockIdx.y * gridDim.x + blockIdx.x;
    const int xcd = id & 7, sq = id >> 3;          // sq in [0,96)
    const int m0 = (xcd * 4 + sq / 24) * 128;      // 4 m-rows per XCD
    const int n0 = (sq % 24) * 128;                // x-major within XCD
    const bool vrole = (n0 >= 2048);

    const int gsw = (lane & 7) ^ (lane >> 3);
    const unsigned short* ga[4];
    const unsigned short* gb[4];
    int ldA[4], ldB[4];
#pragma unroll
    for (int i = 0; i < 4; ++i) {
        int row = wave * 32 + i * 8 + (lane >> 3);
        ga[i] = &A[(size_t)(m0 + row) * DMODEL + gsw * 8];
        gb[i] = &Bt[(size_t)(n0 + row) * DMODEL + gsw * 8];
        ldA[i] = (wave * 32 + i * 8) * 64;
        ldB[i] = 8192 + (wave * 32 + i * 8) * 64;
    }
    const int sx = l16 & 7;

    f32x4 acc[4][4];
#pragma unroll
    for (int i = 0; i < 4; ++i)
#pragma unroll
        for (int j = 0; j < 4; ++j)
#pragma unroll
            for (int r = 0; r < 4; ++r) acc[i][j][r] = 0.0f;

    // prologue: K-tile 0 -> buf 0
#pragma unroll
    for (int i = 0; i < 4; ++i) {
        glds16(ga[i], &SLDS[ldA[i]]);
        glds16(gb[i], &SLDS[ldB[i]]);
    }
    __syncthreads();

    int cur = 0;
    for (int kt = 0; kt < 16; ++kt) {
        // issue next tile's stage FIRST (into the other buffer)
        if (kt < 15) {
            const int ko = (kt + 1) * 64;
            unsigned short* dst = &SLDS[(cur ^ 1) * 16384];
#pragma unroll
            for (int i = 0; i < 4; ++i) {
                glds16(ga[i] + ko, dst + ldA[i]);
                glds16(gb[i] + ko, dst + ldB[i]);
            }
        }
        // compute current tile from buf[cur]
        const unsigned short* Asm = &SLDS[cur * 16384];
        const unsigned short* Bsm = Asm + 8192;
#pragma unroll
        for (int s = 0; s < 2; ++s) {
            bf16x8 af[4], bfr[4];
#pragma unroll
            for (int i = 0; i < 4; ++i)
                af[i] = *(const bf16x8*)&Asm[(wm + i * 16 + l16) * 64 + ((4 * s + quad) ^ sx) * 8];
#pragma unroll
            for (int j = 0; j < 4; ++j)
                bfr[j] = *(const bf16x8*)&Bsm[(wn + j * 16 + l16) * 64 + ((4 * s + quad) ^ sx) * 8];
            __builtin_amdgcn_s_setprio(1);
            if (!vrole) {
#pragma unroll
                for (int i = 0; i < 4; ++i)
#pragma unroll
                    for (int j = 0; j < 4; ++j)
                        acc[i][j] = __builtin_amdgcn_mfma_f32_16x16x32_bf16(af[i], bfr[j], acc[i][j], 0, 0, 0);
            } else {   // C^T: rows=features, cols=tokens
#pragma unroll
                for (int i = 0; i < 4; ++i)
#pragma unroll
                    for (int j = 0; j < 4; ++j)
                        acc[i][j] = __builtin_amdgcn_mfma_f32_16x16x32_bf16(bfr[j], af[i], acc[i][j], 0, 0, 0);
            }
            __builtin_amdgcn_s_setprio(0);
        }
        __syncthreads();   // vmcnt(0)+lgkmcnt(0)+barrier: next buf ready, reads done
        cur ^= 1;
    }

    // ---- epilogue: acc -> swizzled LDS tile [128][128] -> coalesced stores
    const float qscale = 0.1803368801111244f;   // 0.125 * log2(e)
    const float scl = (!vrole && n0 < 1024) ? qscale : 1.0f;
#pragma unroll
    for (int i = 0; i < 4; ++i)
#pragma unroll
        for (int r = 0; r < 4; ++r) {
#pragma unroll
            for (int j = 0; j < 4; ++j) {
                int row_l, col_l;
                if (!vrole) {            // [token][feature]
                    row_l = wm + i * 16 + quad * 4 + r;
                    col_l = wn + j * 16 + l16;
                } else {                 // [feature][token] (acc is C^T)
                    row_l = wn + j * 16 + quad * 4 + r;
                    col_l = wm + i * 16 + l16;
                }
                int key = row_l & 7;
                SLDS[row_l * 128 + (((col_l >> 3) ^ key) * 8) + (col_l & 7)] =
                    f2b(acc[i][j][r] * scl);
            }
        }
    __syncthreads();

    const int s0 = n0 >> 10;        // 0=Q, 1=K (vrole handled separately)
    const int bb = m0 >> 11;        // batch index (tile never crosses)
#pragma unroll
    for (int it = 0; it < 4; ++it) {
        int row = it * 32 + (t >> 3);
        int c = t & 7;
        int key = row & 7;
        bf16x8 v0 = *(const bf16x8*)&SLDS[row * 128 + ((c ^ key) * 8)];
        bf16x8 v1 = *(const bf16x8*)&SLDS[row * 128 + (((c + 8) ^ key) * 8)];
        if (!vrole) {
            int token = m0 + row, lp = token & (L_SEQ - 1);
            int n_a = n0 + c * 8,        h_a = (n_a >> 6) & 15, d_a = n_a & 63;
            int n_b = n0 + (c + 8) * 8,  h_b = (n_b >> 6) & 15, d_b = n_b & 63;
            size_t base = (size_t)s0 * SEG;
            *(bf16x8*)&Cb[base + (((size_t)(bb * NHEADS + h_a) * L_SEQ + lp) * DHEAD) + d_a] = v0;
            *(bf16x8*)&Cb[base + (((size_t)(bb * NHEADS + h_b) * L_SEQ + lp) * DHEAD) + d_b] = v1;
        } else {
            int fr = (n0 - 2048) + row;
            int h = fr >> 6, dd = fr & 63;
            int lp0 = (m0 & (L_SEQ - 1));
            size_t base = 2 * (size_t)SEG +
                          (((size_t)(bb * NHEADS + h) * DHEAD + dd) * L_SEQ) + lp0;
            *(bf16x8*)&Cb[base + c * 8]       = v0;
            *(bf16x8*)&Cb[base + (c + 8) * 8] = v1;
        }
    }
}

// ---------------------------------------------------------------------------
// proj GEMM: out = ao[4096,1024] @ wprojT[1024,1024]^T, fp32 store.
// 128x128 tile + 2-phase dbuf pipeline. Grid 8x32 = 256 blocks; XCD remap.
// ---------------------------------------------------------------------------
__global__ __launch_bounds__(256)
void gemm_proj(const unsigned short* __restrict__ A, const unsigned short* __restrict__ Bt,
               float* __restrict__ Cf) {
    __shared__ unsigned short SLDS[2 * 128 * 128];   // 64 KB

    const int t = threadIdx.x;
    const int lane = t & 63, wave = t >> 6;
    const int quad = lane >> 4, l16 = lane & 15;
    const int wm = (wave >> 1) * 64, wn = (wave & 1) * 64;
    // XCD remap: grid must be 8x32 (256 blocks)
    const int id = blockIdx.y * gridDim.x + blockIdx.x;
    const int xcd = id & 7, sq = id >> 3;          // sq in [0,32)
    const int m0 = (xcd * 4 + (sq >> 3)) * 128;    // 4 m-rows per XCD
    const int n0 = (sq & 7) * 128;

    const int gsw = (lane & 7) ^ (lane >> 3);
    const unsigned short* ga[4];
    const unsigned short* gb[4];
    int ldA[4], ldB[4];
#pragma unroll
    for (int i = 0; i < 4; ++i) {
        int row = wave * 32 + i * 8 + (lane >> 3);
        ga[i] = &A[(size_t)(m0 + row) * DMODEL + gsw * 8];
        gb[i] = &Bt[(size_t)(n0 + row) * DMODEL + gsw * 8];
        ldA[i] = (wave * 32 + i * 8) * 64;
        ldB[i] = 8192 + (wave * 32 + i * 8) * 64;
    }
    const int sx = l16 & 7;

    f32x4 acc[4][4];
#pragma unroll
    for (int i = 0; i < 4; ++i)
#pragma unroll
        for (int j = 0; j < 4; ++j)
#pragma unroll
            for (int r = 0; r < 4; ++r) acc[i][j][r] = 0.0f;

#pragma unroll
    for (int i = 0; i < 4; ++i) {
        glds16(ga[i], &SLDS[ldA[i]]);
        glds16(gb[i], &SLDS[ldB[i]]);
    }
    __syncthreads();

    int cur = 0;
    for (int kt = 0; kt < 16; ++kt) {
        if (kt < 15) {
            const int ko = (kt + 1) * 64;
            unsigned short* dst = &SLDS[(cur ^ 1) * 16384];
#pragma unroll
            for (int i = 0; i < 4; ++i) {
                glds16(ga[i] + ko, dst + ldA[i]);
                glds16(gb[i] + ko, dst + ldB[i]);
            }
        }
        const unsigned short* Asm = &SLDS[cur * 16384];
        const unsigned short* Bsm = Asm + 8192;
#pragma unroll
        for (int s = 0; s < 2; ++s) {
            bf16x8 af[4], bfr[4];
#pragma unroll
            for (int i = 0; i < 4; ++i)
                af[i] = *(const bf16x8*)&Asm[(wm + i * 16 + l16) * 64 + ((4 * s + quad) ^ sx) * 8];
#pragma unroll
            for (int j = 0; j < 4; ++j)
                bfr[j] = *(const bf16x8*)&Bsm[(wn + j * 16 + l16) * 64 + ((4 * s + quad) ^ sx) * 8];
            __builtin_amdgcn_s_setprio(1);
#pragma unroll
            for (int i = 0; i < 4; ++i)
#pragma unroll
                for (int j = 0; j < 4; ++j)
                    acc[i][j] = __builtin_amdgcn_mfma_f32_16x16x32_bf16(af[i], bfr[j], acc[i][j], 0, 0, 0);
            __builtin_amdgcn_s_setprio(0);
        }
        __syncthreads();
        cur ^= 1;
    }

#pragma unroll
    for (int i = 0; i < 4; ++i)
#pragma unroll
        for (int r = 0; r < 4; ++r) {
            int row = m0 + wm + i * 16 + quad * 4 + r;
#pragma unroll
            for (int j = 0; j < 4; ++j)
                Cf[(size_t)row * DMODEL + n0 + wn + j * 16 + l16] = acc[i][j][r];
        }
}

// ---------------------------------------------------------------------------
// Flash causal attention, FAT-Q blocks: 128 q-rows per block, 8 waves =
// 4 q-subtiles (qh in [0,4)) x 2 key-parities (kp in [0,2), 64-key windows).
// Wave-level inner code is verbatim r2's proven version (ST[2] S^T MFMA,
// P via per-wave LDS, 8-chunk PV). Rationale: r2/r3/r4 all land ~45-52us
// with wildly different VALU/conflict profiles -> per-strip lockstep
// overhead dominates. Halving block-strips (8704 -> 4352) at constant
// per-strip stage bytes (32KB) amortizes that fixed cost over 2x work.
// Grid 512 = 32 bh x 16 q-tiles(128q), LPT. LDS: K 16K | V 16K | P 32K =
// 64KB -> 2 blocks/CU (= grid's 512/256 anyway).
// Fixed-max softmax (Q pre-scaled to log2 units); single-round kp merge.
// ---------------------------------------------------------------------------
__global__ __launch_bounds__(512)
void attn_mfma(const unsigned short* __restrict__ Qg, const unsigned short* __restrict__ Kg,
               const unsigned short* __restrict__ Vg, unsigned short* __restrict__ Ao) {
    __shared__ unsigned short SLDS[32768];   // K 16KB | V 16KB | P 32KB
    __shared__ float Rex[128];               // 4 qh x 32 rs partials (kp=1)
    unsigned short* Ksm = SLDS;              // keys: 128 rows x 8 chunks
    unsigned short* Vsm = SLDS + 8192;       // d: 64 rows x 16 key-chunks
    unsigned short* Psm = SLDS + 16384;      // per-wave 32q x 8 key-chunks (4KB)

    const int t = threadIdx.x;
    const int lane = t & 63, wave = t >> 6;        // 8 waves
    const int l31 = lane & 31, hi = lane >> 5;
    const int bh = blockIdx.x & 31;
    const int Qt = 15 - (blockIdx.x >> 5);         // heavy tiles first
    const int q0 = Qt * 128;
    const int qh = wave & 3, kp = wave >> 2;       // qh: 32q row group; kp: 64-key half
    const int wq0 = q0 + qh * 32;
    const int nstrip = Qt + 1;                     // 128-key strips
    const int b = bh >> 4, h = bh & 15;
    const size_t qkbase = (size_t)bh * L_SEQ * DHEAD;
    const size_t vbase  = (size_t)bh * DHEAD * L_SEQ;

    // Q B-frags: n=q=l31(+wq0), k = ks*16 + hi*8 + j
    bf16x8 bq[4];
#pragma unroll
    for (int ks = 0; ks < 4; ++ks)
        bq[ks] = *(const bf16x8*)&Qg[qkbase + (size_t)(wq0 + l31) * DHEAD + ks * 16 + hi * 8];

    // staging assignments (512 threads: 2 rows each)
    const int kc0 = t & 7,  kr0 = (t >> 3) * 2;    // K: rows kr0..+1, chunk kc0
    const int vc0 = t & 15, vd0 = (t >> 4) * 2;    // V: d vd0..+1, chunk vc0

    unsigned short* Pw = Psm + wave * 2048;        // 32q x 64k bf16 = 4KB

    f32x16 O0, O1;
#pragma unroll
    for (int r = 0; r < 16; ++r) { O0[r] = 0.0f; O1[r] = 0.0f; }
    float rs = 0.0f;

    bf16x8 gk[2], gv[2];
#pragma unroll
    for (int i = 0; i < 2; ++i) {
        gk[i] = *(const bf16x8*)&Kg[qkbase + (size_t)(kr0 + i) * DHEAD + kc0 * 8];
        gv[i] = *(const bf16x8*)&Vg[vbase + (size_t)(vd0 + i) * L_SEQ + vc0 * 8];
    }

    for (int s = 0; s < nstrip; ++s) {
        __syncthreads();   // prior strip's LDS reads complete
#pragma unroll
        for (int i = 0; i < 2; ++i) {
            *(bf16x8*)&Ksm[(kc0 * 128 + ((kr0 + i) ^ kc0)) * 8] = gk[i];
            *(bf16x8*)&Vsm[(vc0 * 64 + ((vd0 + i) ^ vc0)) * 8] = gv[i];
        }
        if (s + 1 < nstrip) {
            const int kn = (s + 1) * 128;
#pragma unroll
            for (int i = 0; i < 2; ++i) {
                gk[i] = *(const bf16x8*)&Kg[qkbase + (size_t)(kn + kr0 + i) * DHEAD + kc0 * 8];
                gv[i] = *(const bf16x8*)&Vg[vbase + (size_t)(vd0 + i) * L_SEQ + kn + vc0 * 8];
            }
        }
        __syncthreads();

        const int keybase = s * 128 + kp * 64;     // wave's 64-key window
        if (keybase <= wq0 + 31) {
            // S^T = K·Q^T (rows=keys, cols=q)
            f32x16 ST[2];
            __builtin_amdgcn_s_setprio(1);
#pragma unroll
            for (int kh = 0; kh < 2; ++kh) {
#pragma unroll
                for (int r = 0; r < 16; ++r) ST[kh][r] = 0.0f;
#pragma unroll
                for (int ks = 0; ks < 4; ++ks) {
                    const int c = ks * 2 + hi;
                    const int rk = kp * 64 + kh * 32 + l31;
                    bf16x8 a = *(const bf16x8*)&Ksm[(c * 128 + (rk ^ c)) * 8];
                    ST[kh] = __builtin_amdgcn_mfma_f32_32x32x16_bf16(a, bq[ks], ST[kh], 0, 0, 0);
                }
            }
            __builtin_amdgcn_s_setprio(0);

            if (keybase + 63 > wq0) {   // diagonal: causal mask
                const int qg = wq0 + l31;
#pragma unroll
                for (int kh = 0; kh < 2; ++kh)
#pragma unroll
                    for (int r = 0; r < 16; ++r) {
                        int keyg = keybase + kh * 32 + (r & 3) + 8 * (r >> 2) + 4 * hi;
                        if (keyg > qg) ST[kh][r] = -1e30f;
                    }
            }

            // fixed-max softmax + pack P (wave-local 64-key strip)
#pragma unroll
            for (int kh = 0; kh < 2; ++kh)
#pragma unroll
                for (int g = 0; g < 4; ++g) {
                    float p0 = __builtin_amdgcn_exp2f(ST[kh][4 * g + 0]);
                    float p1 = __builtin_amdgcn_exp2f(ST[kh][4 * g + 1]);
                    float p2 = __builtin_amdgcn_exp2f(ST[kh][4 * g + 2]);
                    float p3 = __builtin_amdgcn_exp2f(ST[kh][4 * g + 3]);
                    rs += (p0 + p1) + (p2 + p3);
                    const int c = kh * 4 + g;
                    *(uint2*)&Pw[(c * 32 + (l31 ^ c)) * 8 + hi * 4] =
                        make_uint2(pk2(p0, p1), pk2(p2, p3));
                }

            // O += P·V  (wave's 64 keys)
            __builtin_amdgcn_s_setprio(1);
#pragma unroll
            for (int ks = 0; ks < 4; ++ks) {
                const int cp = ks * 2 + hi;
                const int cv = kp * 8 + cp;
                bf16x8 pa = *(const bf16x8*)&Pw[(cp * 32 + (l31 ^ cp)) * 8];
                bf16x8 v0 = *(const bf16x8*)&Vsm[(cv * 64 + (l31 ^ cv)) * 8];
                bf16x8 v1 = *(const bf16x8*)&Vsm[(cv * 64 + ((32 + l31) ^ cv)) * 8];
                O0 = __builtin_amdgcn_mfma_f32_32x32x16_bf16(pa, v0, O0, 0, 0, 0);
                O1 = __builtin_amdgcn_mfma_f32_32x32x16_bf16(pa, v1, O1, 0, 0, 0);
            }
            __builtin_amdgcn_s_setprio(0);
        }
    }

    rs += __shfl_xor(rs, 32, 64);   // combine hi halves: full own-window sum, q=l31

    // merge key-parities: kp=1 -> LDS -> kp=0 adds, normalizes, stores
    __syncthreads();                 // all PV reads of K/V LDS done
    float* Oex = (float*)SLDS;       // 4 qh x 32q x 64d f32 = 32768 B exactly
    if (kp == 1) {
#pragma unroll
        for (int r = 0; r < 16; ++r) {
            int qloc = (r & 3) + 8 * (r >> 2) + 4 * hi;
            Oex[qh * 2048 + qloc * 64 + l31]      = O0[r];
            Oex[qh * 2048 + qloc * 64 + 32 + l31] = O1[r];
        }
        if (hi == 0) Rex[qh * 32 + l31] = rs;
    }
    __syncthreads();
    if (kp == 0) {
        float rs_tot = rs + Rex[qh * 32 + l31];
        float linv = 1.0f / rs_tot;
        float lf[16];
#pragma unroll
        for (int r = 0; r < 16; ++r) {
            int qloc = (r & 3) + 8 * (r >> 2) + 4 * hi;
            O0[r] += Oex[qh * 2048 + qloc * 64 + l31];
            O1[r] += Oex[qh * 2048 + qloc * 64 + 32 + l31];
            lf[r] = __shfl(linv, qloc, 32);
        }
#pragma unroll
        for (int r = 0; r < 16; ++r) {
            int qloc = (r & 3) + 8 * (r >> 2) + 4 * hi;
            int token = wq0 + qloc;
            size_t ob = ((size_t)(b * L_SEQ + token)) * DMODEL + h * DHEAD;
            Ao[ob + l31]      = f2b(O0[r] * lf[r]);
            Ao[ob + 32 + l31] = f2b(O1[r] * lf[r]);
        }
    }
}

// ---------------------------------------------------------------------------
extern "C" void kernel_launch(void* const* d_in, const int* in_sizes, int n_in,
                              void* d_out, int out_size, void* d_ws, size_t ws_size,
                              hipStream_t stream) {
    const float* x      = (const float*)d_in[0];   // [B, L, D]
    const float* w_qkv  = (const float*)d_in[1];   // [D, 3D]
    const float* w_proj = (const float*)d_in[2];   // [D, D]
    // d_in[3] num_prefix_tokens: unused — reference mask reduces to pure causal.
    float* out = (float*)d_out;                    // [B, L, D] fp32

    unsigned short* ws     = (unsigned short*)d_ws;
    unsigned short* xb     = ws;                         // 4,194,304
    unsigned short* wqkvT  = xb + 4194304;               // 3,145,728  [3072][1024]
    unsigned short* wprojT = wqkvT + 3145728;            // 1,048,576  [1024][1024]
    unsigned short* qkv    = wprojT + 1048576;           // Q,K [bh][l][d]; V^T [bh][d][l]
    unsigned short* ao     = qkv + 3 * (size_t)SEG;      // 4,194,304

    prep<<<5120, 256, 0, stream>>>(x, w_qkv, w_proj, xb, wqkvT, wprojT);

    gemm_qkv<<<dim3(24, 32), 256, 0, stream>>>(xb, wqkvT, qkv);

    attn_mfma<<<512, 512, 0, stream>>>(qkv, qkv + SEG, qkv + 2 * (size_t)SEG, ao);

    gemm_proj<<<dim3(8, 32), 256, 0, stream>>>(ao, wprojT, out);
}